// Round 7
// baseline (174.931 us; speedup 1.0000x reference)
//
#include <hip/hip_runtime.h>
#include <hip/hip_bf16.h>
#include <cstddef>

// Problem constants (from reference setup_inputs)
#define BB 16
#define CC 192
#define HH 64
#define WW 64
#define LL 4096   // H*W
#define DTR 12    // dt_rank
#define KK 14     // dt_rank + 2*d_state, d_state = 1

__device__ __forceinline__ float silu_f(float v) {
  return v / (1.f + __expf(-v));
}

// ---------------------------------------------------------------------------
// K1: depthwise 5x5 conv (SAME, zero pad) + bias + SiLU — LDS-free.
// One block (4 waves) per (b,c) plane; wave w owns output rows 16w..16w+15.
// Lane = x column. Preload all 20 input rows (2-row halo each side) into
// registers, then 4 shuffles per row + ring of 5 output-row accumulators.
// ---------------------------------------------------------------------------
__global__ __launch_bounds__(256) void conv_silu_kernel(
    const float* __restrict__ x, const float* __restrict__ cw,
    const float* __restrict__ cb, float* __restrict__ xs) {
  const int bc = blockIdx.x;           // b*CC + c
  const int c = bc % CC;
  const int tid = threadIdx.x;
  const int lane = tid & 63;           // x column 0..63
  const int wv = tid >> 6;             // wave 0..3
  const int oy0 = wv * 16;             // first output row of this wave

  float w[25];
#pragma unroll
  for (int k = 0; k < 25; ++k) w[k] = cw[c * 25 + k];
  const float bias = cb[c];

  const float* xp = x + (size_t)bc * LL + lane;
  float* op = xs + (size_t)bc * LL + lane;

  float rv[20];
#pragma unroll
  for (int r = 0; r < 20; ++r) {
    const int gr = oy0 + r - 2;
    float v = 0.f;
    if ((unsigned)gr < 64u) v = xp[gr * 64];
    rv[r] = v;
  }

  float acc[5];
#pragma unroll
  for (int i = 0; i < 5; ++i) acc[i] = 0.f;

#pragma unroll
  for (int r = 0; r < 20; ++r) {
    float v = rv[r];
    float vm2 = __shfl_up(v, 2u, 64);
    float vm1 = __shfl_up(v, 1u, 64);
    float vp1 = __shfl_down(v, 1u, 64);
    float vp2 = __shfl_down(v, 2u, 64);
    if (lane < 2) vm2 = 0.f;
    if (lane < 1) vm1 = 0.f;
    if (lane > 62) vp1 = 0.f;
    if (lane > 61) vp2 = 0.f;
    float t[5] = {vm2, vm1, v, vp1, vp2};
#pragma unroll
    for (int ky = 0; ky < 5; ++ky) {
      if (r >= ky && (r - ky) < 16) {        // static under unroll
        float s = acc[(r - ky) % 5];
#pragma unroll
        for (int kx = 0; kx < 5; ++kx) s += w[ky * 5 + kx] * t[kx];
        acc[(r - ky) % 5] = s;
      }
    }
    if (r >= 4) {                            // static under unroll
      const int yf = oy0 + r - 4;
      float a = acc[(r - 4) % 5] + bias;
      op[yf * 64] = silu_f(a);
      acc[(r - 4) % 5] = 0.f;
    }
  }
}

// ---------------------------------------------------------------------------
// K2: x_dbl[b][k][l] = sum_c x_proj_w[k][c] * xs[b][c][l]   (k = 0..13)
// block = (128-l strip, b), 512 threads = 8 waves x 24 channels; lane owns
// 2 l's (float2, lane-contiguous). Padded LDS partials, one reduce.
// ---------------------------------------------------------------------------
__global__ __launch_bounds__(512) void proj_kernel(
    const float* __restrict__ xs, const float* __restrict__ xpw,
    float* __restrict__ xdbl) {
  const int b = blockIdx.y;
  const int l0 = blockIdx.x * 128;
  const int tid = threadIdx.x;
  const int lane = tid & 63;
  const int g = tid >> 6;  // wave id, 0..7

  __shared__ float part[8][KK][132];   // pad 128->132 to break p-stride

  float2 acc[KK];
#pragma unroll
  for (int k = 0; k < KK; ++k) acc[k] = make_float2(0.f, 0.f);

  const float* bp = xs + ((size_t)(b * CC + g * 24)) * LL + l0 + lane * 2;
#pragma unroll 4
  for (int cc = 0; cc < 24; ++cc) {
    float2 v = *(const float2*)(bp + (size_t)cc * LL);
    const int c = g * 24 + cc;
#pragma unroll
    for (int k = 0; k < KK; ++k) {
      float wv = xpw[k * CC + c];
      acc[k].x += wv * v.x;
      acc[k].y += wv * v.y;
    }
  }
#pragma unroll
  for (int k = 0; k < KK; ++k)
    *(float2*)&part[g][k][lane * 2] = acc[k];
  __syncthreads();

  for (int idx = tid; idx < KK * 128; idx += 512) {
    int k = idx >> 7, ln = idx & 127;
    float v = 0.f;
#pragma unroll
    for (int p = 0; p < 8; ++p) v += part[p][k][ln];
    xdbl[((size_t)b * KK + k) * LL + l0 + ln] = v;
  }
}

// ---------------------------------------------------------------------------
// K3: fused dt-projection + softplus + selective scan + output.
// One 1024-thread block (16 waves) per (b,c) sequence. Wave w owns chunk w
// (256 l's; lane owns 4 contiguous, float4). All waves load CONCURRENTLY
// (no serial chunk chain): per-wave shfl scan -> chunk aggregate -> LDS ->
// one barrier -> each wave composes its <=15-entry prefix -> apply + store.
// ---------------------------------------------------------------------------
__global__ __launch_bounds__(1024) void scan_kernel(
    const float* __restrict__ xs, const float* __restrict__ xdbl,
    const float* __restrict__ dtw, const float* __restrict__ dtb,
    const float* __restrict__ A_logs, const float* __restrict__ Ds,
    float* __restrict__ y) {
  const int bc = blockIdx.x;
  const int b = bc / CC;
  const int c = bc - b * CC;
  const int tid = threadIdx.x;
  const int lane = tid & 63;
  const int wv = tid >> 6;             // chunk id 0..15

  const float Ac = -__expf(A_logs[c]);  // d_state = 1
  const float Dc = Ds[c];
  float dw[DTR];
#pragma unroll
  for (int r = 0; r < DTR; ++r) dw[r] = dtw[c * DTR + r];
  const float db = dtb[c];

  const float* xp = xs + (size_t)bc * LL;
  const float* xb = xdbl + (size_t)b * KK * LL;
  float* yp = y + (size_t)bc * LL;

  const int base = wv * 256 + lane * 4;

  // concurrent loads: 15 float4 per lane, all independent
  float4 x4 = *(const float4*)(xp + base);
  float4 B4 = *(const float4*)(xb + 12 * LL + base);
  float4 C4 = *(const float4*)(xb + 13 * LL + base);
  float4 dr[DTR];
#pragma unroll
  for (int r = 0; r < DTR; ++r)
    dr[r] = *(const float4*)(xb + r * LL + base);

  float xx[4] = {x4.x, x4.y, x4.z, x4.w};
  float bb[4] = {B4.x, B4.y, B4.z, B4.w};
  float av[4], bv[4];
  float aggA = 1.f, aggB = 0.f;
#pragma unroll
  for (int q = 0; q < 4; ++q) {
    float z = db;
#pragma unroll
    for (int r = 0; r < DTR; ++r) z += dw[r] * ((&dr[r].x)[q]);
    float delta = (z > 15.f) ? z : __logf(1.f + __expf(z));
    float a = __expf(delta * Ac);
    float be = delta * bb[q] * xx[q];
    av[q] = a;
    bv[q] = be;
    aggA = a * aggA;
    aggB = a * aggB + be;
  }

  // wave-inclusive scan of affine (aggA, aggB)
  float incA = aggA, incB = aggB;
#pragma unroll
  for (int s = 1; s < 64; s <<= 1) {
    float pA = __shfl_up(incA, (unsigned)s, 64);
    float pB = __shfl_up(incB, (unsigned)s, 64);
    if (lane >= s) {
      incB = incA * pB + incB;
      incA = incA * pA;
    }
  }
  // lane-exclusive prefix within chunk
  float eA = __shfl_up(incA, 1u, 64);
  float eB = __shfl_up(incB, 1u, 64);
  if (lane == 0) { eA = 1.f; eB = 0.f; }

  // chunk aggregates -> LDS
  __shared__ float wA[16], wB[16];
  if (lane == 63) {
    wA[wv] = incA;
    wB[wv] = incB;
  }
  __syncthreads();

  // prefix over chunks 0..wv-1 (h entering this chunk; h_init = 0)
  float pB = 0.f;
  for (int k = 0; k < wv; ++k) pB = wA[k] * pB + wB[k];

  // apply: h at entry of this lane's 4 elements
  float h = eA * pB + eB;
  float ov[4];
#pragma unroll
  for (int q = 0; q < 4; ++q) {
    h = av[q] * h + bv[q];
    ov[q] = h * ((&C4.x)[q]) + xx[q] * Dc;
  }
  float4 o;
  o.x = ov[0]; o.y = ov[1]; o.z = ov[2]; o.w = ov[3];
  *(float4*)(yp + base) = o;
}

// ---------------------------------------------------------------------------
extern "C" void kernel_launch(void* const* d_in, const int* in_sizes, int n_in,
                              void* d_out, int out_size, void* d_ws,
                              size_t ws_size, hipStream_t stream) {
  const float* x        = (const float*)d_in[0];
  const float* conv_w   = (const float*)d_in[1];
  const float* conv_b   = (const float*)d_in[2];
  const float* x_proj_w = (const float*)d_in[3];
  const float* dt_w     = (const float*)d_in[4];
  const float* dt_b     = (const float*)d_in[5];
  const float* A_logs   = (const float*)d_in[6];
  const float* Ds       = (const float*)d_in[7];
  float* out = (float*)d_out;

  char* ws = (char*)d_ws;
  const size_t plane_bytes = (size_t)BB * CC * LL * sizeof(float);  // 50 MB
  float* xs   = (float*)ws;
  float* xdbl = (float*)(ws + plane_bytes);  // BB*KK*LL floats = 3.67 MB

  conv_silu_kernel<<<dim3(BB * CC), 256, 0, stream>>>(x, conv_w, conv_b, xs);
  proj_kernel<<<dim3(LL / 128, BB), 512, 0, stream>>>(xs, x_proj_w, xdbl);
  scan_kernel<<<dim3(BB * CC), 1024, 0, stream>>>(xs, xdbl, dt_w, dt_b,
                                                  A_logs, Ds, out);
}